// Round 1
// baseline (575.906 us; speedup 1.0000x reference)
//
#include <hip/hip_runtime.h>

// SOM forward: x[128,256] f32, weights[64,64,256] f32
// out (f32, concatenated): bmus[128,2] (256 elems) then diffs[128,64,64,256]
#define BATCH 128
#define SOM_ROWS 64
#define SOM_COLS 64
#define M (SOM_ROWS * SOM_COLS)  // 4096
#define D 256
#define DV (D / 4)               // 64 float4 per row == one wave's lanes

// One wave per (b, m) row: lane i handles float4 i of the D=256 row.
// Computes diff = x[b] - w[m], stores it, and wave-reduces sum(diff^2) -> ws.
__global__ void som_diffs_dist(const float* __restrict__ x,
                               const float* __restrict__ w,
                               float* __restrict__ diffs,   // [B*M*D]
                               float* __restrict__ d2ws) {  // [B*M]
  const int lane = threadIdx.x & 63;
  const int wave_in_block = threadIdx.x >> 6;
  const int waves_per_block = blockDim.x >> 6;
  const long gwave = (long)blockIdx.x * waves_per_block + wave_in_block;
  const long nwaves = (long)gridDim.x * waves_per_block;

  const float4* __restrict__ x4 = (const float4*)x;
  const float4* __restrict__ w4 = (const float4*)w;
  float4* __restrict__ o4 = (float4*)diffs;

  const long nrows = (long)BATCH * M;
  for (long r = gwave; r < nrows; r += nwaves) {
    const int b = (int)(r >> 12);       // r / 4096
    const int m = (int)(r & (M - 1));   // r % 4096
    const float4 xv = x4[b * DV + lane];
    const float4 wv = w4[m * DV + lane];
    float4 dv;
    dv.x = xv.x - wv.x;
    dv.y = xv.y - wv.y;
    dv.z = xv.z - wv.z;
    dv.w = xv.w - wv.w;
    o4[r * DV + lane] = dv;
    float s = dv.x * dv.x + dv.y * dv.y + dv.z * dv.z + dv.w * dv.w;
#pragma unroll
    for (int off = 32; off; off >>= 1) s += __shfl_xor(s, off, 64);
    if (lane == 0) d2ws[r] = s;
  }
}

// One block per batch element: argmin over M=4096 d2 values, first-index
// tie-break (matches jnp.argmin). Writes (row, col) as floats.
__global__ void som_argmin(const float* __restrict__ d2ws,
                           float* __restrict__ out) {
  __shared__ float sval[256];
  __shared__ int sidx[256];
  const int b = blockIdx.x;
  const int t = threadIdx.x;
  float best = 3.4e38f;
  int bidx = 0x7fffffff;
  for (int m = t; m < M; m += 256) {
    const float v = d2ws[b * M + m];
    if (v < best) {  // strict <: keeps earliest index within this thread
      best = v;
      bidx = m;
    }
  }
  sval[t] = best;
  sidx[t] = bidx;
  __syncthreads();
  for (int s = 128; s; s >>= 1) {
    if (t < s) {
      const float v2 = sval[t + s];
      const int i2 = sidx[t + s];
      if (v2 < sval[t] || (v2 == sval[t] && i2 < sidx[t])) {
        sval[t] = v2;
        sidx[t] = i2;
      }
    }
    __syncthreads();
  }
  if (t == 0) {
    out[2 * b] = (float)(sidx[0] / SOM_COLS);
    out[2 * b + 1] = (float)(sidx[0] % SOM_COLS);
  }
}

extern "C" void kernel_launch(void* const* d_in, const int* in_sizes, int n_in,
                              void* d_out, int out_size, void* d_ws,
                              size_t ws_size, hipStream_t stream) {
  const float* x = (const float*)d_in[0];       // [128,256]
  const float* w = (const float*)d_in[1];       // [64,64,256]
  float* out = (float*)d_out;
  float* bmus = out;                            // first 256 floats
  float* diffs = out + 2 * BATCH;               // then 128*64*64*256
  float* d2ws = (float*)d_ws;                   // 128*4096 floats = 2 MB

  // 2048 blocks * 4 waves = 8192 waves; 524288 rows -> 64 rows/wave.
  som_diffs_dist<<<2048, 256, 0, stream>>>(x, w, diffs, d2ws);
  som_argmin<<<BATCH, 256, 0, stream>>>(d2ws, bmus);
}